// Round 22
// baseline (286.480 us; speedup 1.0000x reference)
//
#include <hip/hip_runtime.h>

#define NB 8192
#define NT 365
#define NF 5
#define NH 10
#define NG 40   // 4*NH

typedef double d4 __attribute__((ext_vector_type(4)));

// One wave owns 16 batch elements (n = lane&15). Per step a K-chained
// MFMA-f64 group computes all 40 gate pre-activations for all 16 elements:
//   G(48x16, 40 valid rows) = A(48x16) * B(16x16)
// A = [W_hh | W_ih | bias] with K rows j: 0..9 = h, 10..14 = x, 15 = 1.
// The MFMA's internal all-to-all replaces the 10 ds_bpermute/step of the
// VALU kernels: h_j's producer lane IS the B-slot lane for K row j.
// f64 MFMA is exact for fp32 inputs. g-gate rows pre-scaled x2
// (tanh(z) = 2*sigmoid(2z)-1). x gathered per-lane 2 steps ahead.
//
// r21 failed correctness (absmax 0.67) -- the one unverified assumption is
// the f64 D-row mapping. Two candidates:
//   m1: row = 4*(lane>>4) + reg   (bf16-verified pattern)
//   m2: row = (lane>>4) + 4*reg   (interleaved f64 pattern)
// Under m1 the A row-order (unit=R>>2, gate=R&3) makes lane regs = 4 gates
// of one unit; under m2 the order (unit=R&3, gate=R>>2) does -- everything
// else (B feeds, stores, fc) is IDENTICAL under both. A runtime probe MFMA
// (A = row index on k=0, B = e0 -> D[i][j] = i) selects the mapping.
__global__ __launch_bounds__(64, 1)
void lstm_mfma2(const float* __restrict__ x,
                const float* __restrict__ w_ih,
                const float* __restrict__ w_hh,
                const float* __restrict__ bias,
                const float* __restrict__ fc_w,
                const float* __restrict__ fc_b,
                float* __restrict__ out)
{
    const int lane = threadIdx.x & 63;
    const int n  = lane & 15;        // batch column within wave
    const int g4 = lane >> 4;        // K-slot / D row-group
    const long b = (long)blockIdx.x * 16 + n;

    float* h_out = out + NB;
    float* c_out = h_out + (size_t)NB * NT * NH;

    // ---- D-layout probe: D[i][j] = i for this A,B ----
    bool m1;
    {
        const double Ap = (g4 == 0) ? (double)n : 0.0;   // A[i][0] = i
        const double Bp = (g4 == 0) ? 1.0 : 0.0;         // B[0][j] = 1
        d4 Dp = __builtin_amdgcn_mfma_f64_16x16x4f64(Ap, Bp, (d4)0.0, 0, 0, 0);
        const int r0 = (int)Dp[0];                       // row index of reg 0
        m1 = __all(r0 == (g4 << 2)) != 0;                // else row0 == g4 (m2)
    }

    // ---- A fragments: lane holds A[row=n][k=g4] of each 16-row block m ----
    // m1: G row R = gate (R&3) of unit 4m+(R>>2)
    // m2: G row R = gate (R>>2) of unit 4m+(R&3)
    // Both make lane (g4,n)'s D regs = gates 0..3 (reg=gate) of unit 4m+g4.
    double A[3][4];
    {
        const int upo = m1 ? (n >> 2) : (n & 3);   // unit offset in 4-group
        const int q   = m1 ? (n & 3) : (n >> 2);   // gate (f,i,o,g)
        const float gs = (q == 3) ? 2.0f : 1.0f;
        #pragma unroll
        for (int m = 0; m < 3; ++m) {
            const int up = 4 * m + upo;
            const int c  = q * NH + up;
            #pragma unroll
            for (int kt = 0; kt < 4; ++kt) {
                const int j = 4 * kt + g4;
                double v = 0.0;
                if (up < NH) {
                    if (j < NH)      v = (double)(w_hh[j * NG + c] * gs);
                    else if (j < 15) v = (double)(w_ih[(j - NH) * NG + c] * gs);
                    else             v = (double)(bias[c] * gs);
                }
                A[m][kt] = v;
            }
        }
    }

    // per-lane state: units u' = g4, 4+g4, 8+g4 (3rd valid only g4<2)
    float h0 = 0.f, h1 = 0.f, h2 = 0.f;
    float c0 = 0.f, c1 = 0.f, c2 = 0.f;

    // x gather roles: XV feeds B3 (x2,x3,x4 for g4=0,1,2; g4=3 -> 1.0)
    //                 XW feeds B2 (x0,x1 for g4=2,3)
    const float* xb = x + (size_t)b * NT * NF;
    const bool ld_v = (g4 < 3);
    const bool ld_w = (g4 >= 2);
    const int  fv   = 2 + g4;
    const int  fw   = g4 - 2;

    float* hsp = h_out + (size_t)b * NT * NH + g4;
    float* csp = c_out + (size_t)b * NT * NH + g4;

#define ACT(Dm, hq, cq) { \
    const float gf = (float)Dm[0], gi = (float)Dm[1]; \
    const float go = (float)Dm[2], gg = (float)Dm[3]; \
    const float sf = __builtin_amdgcn_rcpf(1.0f + __expf(-gf)); \
    const float si = __builtin_amdgcn_rcpf(1.0f + __expf(-gi)); \
    const float so = __builtin_amdgcn_rcpf(1.0f + __expf(-go)); \
    const float tg = fmaf(2.0f, __builtin_amdgcn_rcpf(1.0f + __expf(-gg)), -1.0f); \
    cq = fmaf(sf, cq, si * tg); \
    const float th = fmaf(2.0f, __builtin_amdgcn_rcpf(1.0f + __expf(-2.0f * cq)), -1.0f); \
    hq = so * th; }

#define STEP(T, XV, XW) { \
    double B0 = (double)h0, B1 = (double)h1; \
    double B2 = (g4 < 2) ? (double)h2 : (double)XW; \
    double B3 = (g4 == 3) ? 1.0 : (double)XV; \
    { const int tl = ((T) + 2 <= NT - 1) ? (T) + 2 : NT - 1; \
      if (ld_v) XV = xb[(size_t)tl * NF + fv]; \
      if (ld_w) XW = xb[(size_t)tl * NF + fw]; } \
    const d4 Z = (d4)0.0; \
    d4 D0 = __builtin_amdgcn_mfma_f64_16x16x4f64(A[0][0], B0, Z, 0, 0, 0); \
    d4 D1 = __builtin_amdgcn_mfma_f64_16x16x4f64(A[1][0], B0, Z, 0, 0, 0); \
    d4 D2 = __builtin_amdgcn_mfma_f64_16x16x4f64(A[2][0], B0, Z, 0, 0, 0); \
    D0 = __builtin_amdgcn_mfma_f64_16x16x4f64(A[0][1], B1, D0, 0, 0, 0); \
    D1 = __builtin_amdgcn_mfma_f64_16x16x4f64(A[1][1], B1, D1, 0, 0, 0); \
    D2 = __builtin_amdgcn_mfma_f64_16x16x4f64(A[2][1], B1, D2, 0, 0, 0); \
    D0 = __builtin_amdgcn_mfma_f64_16x16x4f64(A[0][2], B2, D0, 0, 0, 0); \
    D1 = __builtin_amdgcn_mfma_f64_16x16x4f64(A[1][2], B2, D1, 0, 0, 0); \
    D2 = __builtin_amdgcn_mfma_f64_16x16x4f64(A[2][2], B2, D2, 0, 0, 0); \
    D0 = __builtin_amdgcn_mfma_f64_16x16x4f64(A[0][3], B3, D0, 0, 0, 0); \
    D1 = __builtin_amdgcn_mfma_f64_16x16x4f64(A[1][3], B3, D1, 0, 0, 0); \
    D2 = __builtin_amdgcn_mfma_f64_16x16x4f64(A[2][3], B3, D2, 0, 0, 0); \
    ACT(D0, h0, c0) \
    ACT(D1, h1, c1) \
    ACT(D2, h2, c2) \
    hsp[0] = h0; hsp[4] = h1; \
    csp[0] = c0; csp[4] = c1; \
    if (g4 < 2) { hsp[8] = h2; csp[8] = c2; } \
    hsp += NH; csp += NH; }

    // prologue: x for t=0 (XA) and t=1 (XB)
    float XAv = 0.f, XAw = 0.f, XBv = 0.f, XBw = 0.f;
    if (ld_v) XAv = xb[fv];
    if (ld_w) XAw = xb[fw];
    if (ld_v) XBv = xb[NF + fv];
    if (ld_w) XBw = xb[NF + fw];

    for (int t = 0; t < NT - 1; t += 2) {   // 182 pairs: t = 0..363
        STEP(t,     XAv, XAw)
        STEP(t + 1, XBv, XBw)
    }
    STEP(NT - 1, XAv, XAw)                  // t = 364 (XA holds x[364])

    // ---- fc head: partial per lane, reduce over the 4 g4 groups ----
    float p = fc_w[g4] * h0 + fc_w[4 + g4] * h1;
    if (g4 < 2) p = fmaf(fc_w[8 + g4], h2, p);
    p += __int_as_float(__builtin_amdgcn_ds_swizzle(__float_as_int(p), 0x401F)); // ^16
    p += __int_as_float(__builtin_amdgcn_ds_bpermute((lane ^ 32) << 2,
                                                     __float_as_int(p)));        // ^32
    if (g4 == 0) out[b] = p + fc_b[0];
}

extern "C" void kernel_launch(void* const* d_in, const int* in_sizes, int n_in,
                              void* d_out, int out_size, void* d_ws, size_t ws_size,
                              hipStream_t stream) {
    const float* x    = (const float*)d_in[0];
    const float* wih  = (const float*)d_in[1];
    const float* whh  = (const float*)d_in[2];
    const float* bias = (const float*)d_in[3];
    const float* fcw  = (const float*)d_in[4];
    const float* fcb  = (const float*)d_in[5];
    float* out = (float*)d_out;

    // one wave per block, 16 batch elements per wave
    lstm_mfma2<<<NB / 16, 64, 0, stream>>>(x, wih, whh, bias, fcw, fcb, out);
}

// Round 23
// 272.352 us; speedup vs baseline: 1.0519x; 1.0519x over previous
//
#include <hip/hip_runtime.h>

#define NB 8192
#define NT 365
#define NF 5
#define NH 10
#define NG 40

typedef short bf16x8 __attribute__((ext_vector_type(8)));
typedef float f32x4  __attribute__((ext_vector_type(4)));

// pack two f32 -> one u32 of 2 bf16 (elem order: first arg = low = even elem)
static __device__ __forceinline__ unsigned pk2(float a, float b) {
    unsigned r;
    asm("v_cvt_pk_bf16_f32 %0, %1, %2" : "=v"(r) : "v"(a), "v"(b));
    return r;
}
static __device__ __forceinline__ bf16x8 mk8(unsigned a, unsigned b, unsigned c, unsigned d) {
    int4 iv; iv.x = (int)a; iv.y = (int)b; iv.z = (int)c; iv.w = (int)d;
    return __builtin_bit_cast(bf16x8, iv);
}
// truncation hi-part: exactly representable in bf16
static __device__ __forceinline__ float hi_f(float v) {
    return __uint_as_float(__float_as_uint(v) & 0xFFFF0000u);
}
static __device__ __forceinline__ float bperm(int sl, float v) {
    return __int_as_float(__builtin_amdgcn_ds_bpermute(sl << 2, __float_as_int(v)));
}

// One wave = 16 batch elements (col n = lane&15). Per step, gates for all 16
// elements via bf16 MFMA 16x16x32 (D-layout HW-verified: col=lane&15,
// row=4*(lane>>4)+reg). G(40x16) rows packed per block m (16 rows): row R ->
// gate q=R&3 (f,i,o,g) of unit u=4m+(R>>2); lane (g4,n)'s D_m regs 0..3 =
// gates f,i,o,g of unit 4m+g4. A rows pre-scaled by -1 (-2 for g-gate) so
// D = -z and sigma = rcp(1+expf(D)).
// Exactness via hi/lo bf16 split (trunc): w*v = w_hi*v_hi + w_lo*v_hi +
// w_hi*v_lo (drop w_lo*v_lo ~2^-16):
//   MFMA1: A1 = [Whh_hi | Wih_hi | bias_hi], B1 = [h_hi | x_hi | 1]  (k0-15)
//   MFMA2: A2 = [Whh_lo k0-9 | Whh_hi k10-19 | Wih_lo k20-24 | Wih_hi k25-29
//                | bias_lo k30], B2 = [h_hi | h_lo | x_hi | x_lo | 1 | 0]
// A/B fragment k-mapping assumed k = 8*(lane>>4)+e (contiguous).
// h redistribution: 10 parallel ds_bpermute (replaces serial VALU chain).
__global__ __launch_bounds__(64, 1)
void lstm_bmfma(const float* __restrict__ x,
                const float* __restrict__ w_ih,
                const float* __restrict__ w_hh,
                const float* __restrict__ bias,
                const float* __restrict__ fc_w,
                const float* __restrict__ fc_b,
                float* __restrict__ out)
{
    const int lane = threadIdx.x & 63;
    const int n  = lane & 15;
    const int g4 = lane >> 4;
    const long b = (long)blockIdx.x * 16 + n;

    float* h_out = out + NB;
    float* c_out = h_out + (size_t)NB * NT * NH;

    // ---- A fragments (load once) ----
    const int   q = n & 3;                    // gate of this A-row
    const float s = (q == 3) ? -2.0f : -1.0f; // bake sign+tanh scale
    bf16x8 A1[3], A2[3];
    #pragma unroll
    for (int m = 0; m < 3; ++m) {
        const int u   = 4 * m + (n >> 2);
        const bool ok = (u < NH);
        const int c   = q * NH + u;
        float v1[8], v2[8];
        #pragma unroll
        for (int e = 0; e < 8; ++e) {
            const int k = 8 * g4 + e;
            float a1 = 0.f, a2 = 0.f;
            if (ok) {
                if (k < 10)       a1 = hi_f(s * w_hh[k * NG + c]);
                else if (k < 15)  a1 = hi_f(s * w_ih[(k - 10) * NG + c]);
                else if (k == 15) a1 = hi_f(s * bias[c]);
                if (k < 10)       { float w = s * w_hh[k * NG + c];        a2 = w - hi_f(w); }
                else if (k < 20)  { float w = s * w_hh[(k - 10) * NG + c]; a2 = hi_f(w); }
                else if (k < 25)  { float w = s * w_ih[(k - 20) * NG + c]; a2 = w - hi_f(w); }
                else if (k < 30)  { float w = s * w_ih[(k - 25) * NG + c]; a2 = hi_f(w); }
                else if (k == 30) { float w = s * bias[c];                 a2 = w - hi_f(w); }
            }
            v1[e] = a1; v2[e] = a2;
        }
        A1[m] = mk8(pk2(v1[0],v1[1]), pk2(v1[2],v1[3]), pk2(v1[4],v1[5]), pk2(v1[6],v1[7]));
        A2[m] = mk8(pk2(v2[0],v2[1]), pk2(v2[2],v2[3]), pk2(v2[4],v2[5]), pk2(v2[6],v2[7]));
    }

    float h0 = 0.f, h1 = 0.f, h2 = 0.f;   // units g4, 4+g4, 8+g4 (g4<2)
    float c0 = 0.f, c1 = 0.f, c2 = 0.f;

    const float* xb = x + (size_t)b * NT * NF;
    float* hsp = h_out + (size_t)b * NT * NH + g4;
    float* csp = c_out + (size_t)b * NT * NH + g4;

#define ACT(D, hq, cq) { \
    const float sf = __builtin_amdgcn_rcpf(1.0f + __expf(D[0])); \
    const float si = __builtin_amdgcn_rcpf(1.0f + __expf(D[1])); \
    const float so = __builtin_amdgcn_rcpf(1.0f + __expf(D[2])); \
    const float tg = fmaf(2.0f, __builtin_amdgcn_rcpf(1.0f + __expf(D[3])), -1.0f); \
    cq = fmaf(sf, cq, si * tg); \
    const float th = fmaf(2.0f, __builtin_amdgcn_rcpf(1.0f + __expf(-2.0f * cq)), -1.0f); \
    hq = so * th; }

#define STEP(T, XR) { \
    const float xh0=hi_f(XR[0]), xh1=hi_f(XR[1]), xh2=hi_f(XR[2]), xh3=hi_f(XR[3]), xh4=hi_f(XR[4]); \
    const float xl0=XR[0]-xh0, xl1=XR[1]-xh1, xl2=XR[2]-xh2, xl3=XR[3]-xh3, xl4=XR[4]-xh4; \
    const float hv0=bperm(n,h0),      hv1=bperm(16+n,h0), hv2=bperm(32+n,h0), hv3=bperm(48+n,h0); \
    const float hv4=bperm(n,h1),      hv5=bperm(16+n,h1), hv6=bperm(32+n,h1), hv7=bperm(48+n,h1); \
    const float hv8=bperm(n,h2),      hv9=bperm(16+n,h2); \
    const float hh0=hi_f(hv0),hh1=hi_f(hv1),hh2=hi_f(hv2),hh3=hi_f(hv3),hh4=hi_f(hv4); \
    const float hh5=hi_f(hv5),hh6=hi_f(hv6),hh7=hi_f(hv7),hh8=hi_f(hv8),hh9=hi_f(hv9); \
    const float hl0=hv0-hh0,hl1=hv1-hh1,hl2=hv2-hh2,hl3=hv3-hh3,hl4=hv4-hh4; \
    const float hl5=hv5-hh5,hl6=hv6-hh6,hl7=hv7-hh7,hl8=hv8-hh8,hl9=hv9-hh9; \
    unsigned r10,r11,r12,r13,r20,r21,r22x,r23; \
    if (g4 == 0) { \
        r10=pk2(hh0,hh1); r11=pk2(hh2,hh3); r12=pk2(hh4,hh5); r13=pk2(hh6,hh7); \
        r20=r10; r21=r11; r22x=r12; r23=r13; \
    } else if (g4 == 1) { \
        r10=pk2(hh8,hh9); r11=pk2(xh0,xh1); r12=pk2(xh2,xh3); r13=pk2(xh4,1.0f); \
        r20=pk2(hh8,hh9); r21=pk2(hl0,hl1); r22x=pk2(hl2,hl3); r23=pk2(hl4,hl5); \
    } else if (g4 == 2) { \
        r10=0u; r11=0u; r12=0u; r13=0u; \
        r20=pk2(hl6,hl7); r21=pk2(hl8,hl9); r22x=pk2(xh0,xh1); r23=pk2(xh2,xh3); \
    } else { \
        r10=0u; r11=0u; r12=0u; r13=0u; \
        r20=pk2(xh4,xl0); r21=pk2(xl1,xl2); r22x=pk2(xl3,xl4); r23=pk2(1.0f,0.0f); \
    } \
    const bf16x8 B1 = mk8(r10,r11,r12,r13); \
    const bf16x8 B2 = mk8(r20,r21,r22x,r23); \
    const f32x4 Z = {0.f,0.f,0.f,0.f}; \
    f32x4 D0 = __builtin_amdgcn_mfma_f32_16x16x32_bf16(A1[0], B1, Z, 0, 0, 0); \
    f32x4 D1 = __builtin_amdgcn_mfma_f32_16x16x32_bf16(A1[1], B1, Z, 0, 0, 0); \
    f32x4 D2 = __builtin_amdgcn_mfma_f32_16x16x32_bf16(A1[2], B1, Z, 0, 0, 0); \
    D0 = __builtin_amdgcn_mfma_f32_16x16x32_bf16(A2[0], B2, D0, 0, 0, 0); \
    D1 = __builtin_amdgcn_mfma_f32_16x16x32_bf16(A2[1], B2, D1, 0, 0, 0); \
    D2 = __builtin_amdgcn_mfma_f32_16x16x32_bf16(A2[2], B2, D2, 0, 0, 0); \
    { const int tl = ((T) + 2 <= NT - 1) ? (T) + 2 : NT - 1; \
      const float* xq = xb + (size_t)tl * NF; \
      XR[0]=xq[0]; XR[1]=xq[1]; XR[2]=xq[2]; XR[3]=xq[3]; XR[4]=xq[4]; } \
    ACT(D0, h0, c0) ACT(D1, h1, c1) ACT(D2, h2, c2) \
    hsp[0] = h0; hsp[4] = h1; csp[0] = c0; csp[4] = c1; \
    if (g4 < 2) { hsp[8] = h2; csp[8] = c2; } \
    hsp += NH; csp += NH; }

    // prologue: x[0] and x[1]
    float XA[5], XB[5];
    #pragma unroll
    for (int f = 0; f < NF; ++f) { XA[f] = xb[f]; XB[f] = xb[NF + f]; }

    for (int t = 0; t < NT - 1; t += 2) {   // 182 pairs: t = 0..363
        STEP(t,     XA)
        STEP(t + 1, XB)
    }
    STEP(NT - 1, XA)                        // t = 364 (XA holds x[364])

    // ---- fc head (r22-verified reduce) ----
    float p = fc_w[g4] * h0 + fc_w[4 + g4] * h1;
    if (g4 < 2) p = fmaf(fc_w[8 + g4], h2, p);
    p += __int_as_float(__builtin_amdgcn_ds_swizzle(__float_as_int(p), 0x401F)); // ^16
    p += __int_as_float(__builtin_amdgcn_ds_bpermute((lane ^ 32) << 2,
                                                     __float_as_int(p)));        // ^32
    if (g4 == 0) out[b] = p + fc_b[0];
}

extern "C" void kernel_launch(void* const* d_in, const int* in_sizes, int n_in,
                              void* d_out, int out_size, void* d_ws, size_t ws_size,
                              hipStream_t stream) {
    const float* x    = (const float*)d_in[0];
    const float* wih  = (const float*)d_in[1];
    const float* whh  = (const float*)d_in[2];
    const float* bias = (const float*)d_in[3];
    const float* fcw  = (const float*)d_in[4];
    const float* fcb  = (const float*)d_in[5];
    float* out = (float*)d_out;

    lstm_bmfma<<<NB / 16, 64, 0, stream>>>(x, wih, whh, bias, fcw, fcb, out);
}

// Round 24
// 221.584 us; speedup vs baseline: 1.2929x; 1.2291x over previous
//
#include <hip/hip_runtime.h>

#define NB 8192
#define NT 365
#define NF 5
#define NH 10
#define NG 40

typedef short bf16x8 __attribute__((ext_vector_type(8)));
typedef float f32x4  __attribute__((ext_vector_type(4)));

// pack two f32 -> one u32 of 2 bf16 (first arg = low/even element)
static __device__ __forceinline__ unsigned pk2(float a, float b) {
    unsigned r;
    asm("v_cvt_pk_bf16_f32 %0, %1, %2" : "=v"(r) : "v"(a), "v"(b));
    return r;
}
static __device__ __forceinline__ bf16x8 mk8(unsigned a, unsigned b, unsigned c, unsigned d) {
    int4 iv; iv.x = (int)a; iv.y = (int)b; iv.z = (int)c; iv.w = (int)d;
    return __builtin_bit_cast(bf16x8, iv);
}
static __device__ __forceinline__ float hi_f(float v) {   // bf16-exact hi part
    return __uint_as_float(__float_as_uint(v) & 0xFFFF0000u);
}
static __device__ __forceinline__ float bperm(int sl, float v) {
    return __int_as_float(__builtin_amdgcn_ds_bpermute(sl << 2, __float_as_int(v)));
}

// Structure identical to r23 (passed, absmax 0.0156): one wave = 16 batch
// elements; 6 bf16 MFMA 16x16x32 per step compute all 40 gates; hi/lo bf16
// split keeps fp32-grade accuracy; A rows pre-scaled by -1 (-2 for g) so
// sigma = rcp(1+expf(D)). Verified pieces kept verbatim: A k-map (k=8*g4+e),
// D-map (col=n, reg=gate of unit 4m+g4), ACT, stores, fc reduce.
//
// FIX vs r23 (272us, 2.56% MfmaUtil, ~1380cyc/step stall): the B-pack was
// 8 divergent exec-mask regions/step (if/else on g4 with asm pk2 inside --
// compiler can't speculate asm, so real branches). Now: all pk2 candidates
// hoisted uniformly, B-words picked with cndmask ternaries; x-side packed
// words precomputed one step ahead of use (off the critical chain) via a
// rotating raw/packed buffer pair. A1 is zero for k>=16 -> B1 needs only a
// 2-way select.
__global__ __launch_bounds__(64, 1)
void lstm_bmfma2(const float* __restrict__ x,
                 const float* __restrict__ w_ih,
                 const float* __restrict__ w_hh,
                 const float* __restrict__ bias,
                 const float* __restrict__ fc_w,
                 const float* __restrict__ fc_b,
                 float* __restrict__ out)
{
    const int lane = threadIdx.x & 63;
    const int n  = lane & 15;
    const int g4 = lane >> 4;
    const long b = (long)blockIdx.x * 16 + n;

    float* h_out = out + NB;
    float* c_out = h_out + (size_t)NB * NT * NH;

    // ---- A fragments (verbatim r23) ----
    const int   q = n & 3;
    const float s = (q == 3) ? -2.0f : -1.0f;
    bf16x8 A1[3], A2[3];
    #pragma unroll
    for (int m = 0; m < 3; ++m) {
        const int u   = 4 * m + (n >> 2);
        const bool ok = (u < NH);
        const int c   = q * NH + u;
        float v1[8], v2[8];
        #pragma unroll
        for (int e = 0; e < 8; ++e) {
            const int k = 8 * g4 + e;
            float a1 = 0.f, a2 = 0.f;
            if (ok) {
                if (k < 10)       a1 = hi_f(s * w_hh[k * NG + c]);
                else if (k < 15)  a1 = hi_f(s * w_ih[(k - 10) * NG + c]);
                else if (k == 15) a1 = hi_f(s * bias[c]);
                if (k < 10)       { float w = s * w_hh[k * NG + c];        a2 = w - hi_f(w); }
                else if (k < 20)  { float w = s * w_hh[(k - 10) * NG + c]; a2 = hi_f(w); }
                else if (k < 25)  { float w = s * w_ih[(k - 20) * NG + c]; a2 = w - hi_f(w); }
                else if (k < 30)  { float w = s * w_ih[(k - 25) * NG + c]; a2 = hi_f(w); }
                else if (k == 30) { float w = s * bias[c];                 a2 = w - hi_f(w); }
            }
            v1[e] = a1; v2[e] = a2;
        }
        A1[m] = mk8(pk2(v1[0],v1[1]), pk2(v1[2],v1[3]), pk2(v1[4],v1[5]), pk2(v1[6],v1[7]));
        A2[m] = mk8(pk2(v2[0],v2[1]), pk2(v2[2],v2[3]), pk2(v2[4],v2[5]), pk2(v2[6],v2[7]));
    }

    const bool g40 = (g4 == 0), g41 = (g4 == 1), g42 = (g4 == 2);
    const unsigned E10 = pk2(1.0f, 0.0f);   // B2 word3 for g4==3: [1, 0]

    float h0 = 0.f, h1 = 0.f, h2 = 0.f;
    float c0 = 0.f, c1 = 0.f, c2 = 0.f;

    const float* xb = x + (size_t)b * NT * NF;
    float* hsp = h_out + (size_t)b * NT * NH + g4;
    float* csp = c_out + (size_t)b * NT * NH + g4;

    // rotating x buffers: raw (5 f32) + packed words (6 u32) per parity
    float RA0,RA1,RA2,RA3,RA4, RB0,RB1,RB2,RB3,RB4;
    unsigned WA_H01,WA_H23,WA_H4b,WA_M,WA_L12,WA_L34;
    unsigned WB_H01,WB_H23,WB_H4b,WB_M,WB_L12,WB_L34;

#define LOADR(S, T) { const int tl_ = ((T) <= NT-1) ? (T) : NT-1; \
    const float* xq_ = xb + (size_t)tl_ * NF; \
    R##S##0 = xq_[0]; R##S##1 = xq_[1]; R##S##2 = xq_[2]; \
    R##S##3 = xq_[3]; R##S##4 = xq_[4]; }

#define PACKW(S) { \
    const float ph0 = hi_f(R##S##0), ph1 = hi_f(R##S##1), ph2 = hi_f(R##S##2); \
    const float ph3 = hi_f(R##S##3), ph4 = hi_f(R##S##4); \
    W##S##_H01 = pk2(ph0, ph1);  W##S##_H23 = pk2(ph2, ph3); \
    W##S##_H4b = pk2(ph4, 1.0f); W##S##_M   = pk2(ph4, R##S##0 - ph0); \
    W##S##_L12 = pk2(R##S##1 - ph1, R##S##2 - ph2); \
    W##S##_L34 = pk2(R##S##3 - ph3, R##S##4 - ph4); }

#define ACT(D, hq, cq) { \
    const float sf = __builtin_amdgcn_rcpf(1.0f + __expf(D[0])); \
    const float si = __builtin_amdgcn_rcpf(1.0f + __expf(D[1])); \
    const float so = __builtin_amdgcn_rcpf(1.0f + __expf(D[2])); \
    const float tg = fmaf(2.0f, __builtin_amdgcn_rcpf(1.0f + __expf(D[3])), -1.0f); \
    cq = fmaf(sf, cq, si * tg); \
    const float th = fmaf(2.0f, __builtin_amdgcn_rcpf(1.0f + __expf(-2.0f * cq)), -1.0f); \
    hq = so * th; }

// STEP(T, U, P): use packed words W_U (= x[T]); reload raw R_U <- x[T+2]
// (buffer just freed); tail: pack W_P <- R_P (loaded last step, arrived).
#define STEP(T, U, P) { \
    const float v0_=bperm(n,h0),    v1_=bperm(16+n,h0), v2_=bperm(32+n,h0), v3_=bperm(48+n,h0); \
    const float v4_=bperm(n,h1),    v5_=bperm(16+n,h1), v6_=bperm(32+n,h1), v7_=bperm(48+n,h1); \
    const float v8_=bperm(n,h2),    v9_=bperm(16+n,h2); \
    const float a0_=hi_f(v0_),a1_=hi_f(v1_),a2_=hi_f(v2_),a3_=hi_f(v3_),a4_=hi_f(v4_); \
    const float a5_=hi_f(v5_),a6_=hi_f(v6_),a7_=hi_f(v7_),a8_=hi_f(v8_),a9_=hi_f(v9_); \
    const unsigned P01=pk2(a0_,a1_), P23=pk2(a2_,a3_), P45=pk2(a4_,a5_); \
    const unsigned P67=pk2(a6_,a7_), P89=pk2(a8_,a9_); \
    const unsigned L01=pk2(v0_-a0_, v1_-a1_), L23=pk2(v2_-a2_, v3_-a3_); \
    const unsigned L45=pk2(v4_-a4_, v5_-a5_), L67=pk2(v6_-a6_, v7_-a7_); \
    const unsigned L89=pk2(v8_-a8_, v9_-a9_); \
    const unsigned B1w0 = g40 ? P01 : P89; \
    const unsigned B1w1 = g40 ? P23 : W##U##_H01; \
    const unsigned B1w2 = g40 ? P45 : W##U##_H23; \
    const unsigned B1w3 = g40 ? P67 : W##U##_H4b; \
    const unsigned B2w0 = g40 ? P01 : (g41 ? P89 : (g42 ? L67 : W##U##_M)); \
    const unsigned B2w1 = g40 ? P23 : (g41 ? L01 : (g42 ? L89 : W##U##_L12)); \
    const unsigned B2w2 = g40 ? P45 : (g41 ? L23 : (g42 ? W##U##_H01 : W##U##_L34)); \
    const unsigned B2w3 = g40 ? P67 : (g41 ? L45 : (g42 ? W##U##_H23 : E10)); \
    const bf16x8 B1 = mk8(B1w0, B1w1, B1w2, B1w3); \
    const bf16x8 B2 = mk8(B2w0, B2w1, B2w2, B2w3); \
    const f32x4 Z = {0.f, 0.f, 0.f, 0.f}; \
    f32x4 D0 = __builtin_amdgcn_mfma_f32_16x16x32_bf16(A1[0], B1, Z, 0, 0, 0); \
    f32x4 D1 = __builtin_amdgcn_mfma_f32_16x16x32_bf16(A1[1], B1, Z, 0, 0, 0); \
    f32x4 D2 = __builtin_amdgcn_mfma_f32_16x16x32_bf16(A1[2], B1, Z, 0, 0, 0); \
    D0 = __builtin_amdgcn_mfma_f32_16x16x32_bf16(A2[0], B2, D0, 0, 0, 0); \
    D1 = __builtin_amdgcn_mfma_f32_16x16x32_bf16(A2[1], B2, D1, 0, 0, 0); \
    D2 = __builtin_amdgcn_mfma_f32_16x16x32_bf16(A2[2], B2, D2, 0, 0, 0); \
    LOADR(U, (T) + 2) \
    ACT(D0, h0, c0) ACT(D1, h1, c1) ACT(D2, h2, c2) \
    hsp[0] = h0; hsp[4] = h1; csp[0] = c0; csp[4] = c1; \
    if (g4 < 2) { hsp[8] = h2; csp[8] = c2; } \
    hsp += NH; csp += NH; \
    PACKW(P) }

    // prologue: raw x[0], x[1]; pack both
    LOADR(A, 0) LOADR(B, 1)
    PACKW(A) PACKW(B)

    for (int t = 0; t < NT - 1; t += 2) {   // t = 0..362 (182 iters)
        STEP(t,     A, B)
        STEP(t + 1, B, A)
    }
    STEP(NT - 1, A, B)                      // t = 364; WA packed last iter

    // ---- fc head (verbatim r23, verified) ----
    float p = fc_w[g4] * h0 + fc_w[4 + g4] * h1;
    if (g4 < 2) p = fmaf(fc_w[8 + g4], h2, p);
    p += __int_as_float(__builtin_amdgcn_ds_swizzle(__float_as_int(p), 0x401F)); // ^16
    p += __int_as_float(__builtin_amdgcn_ds_bpermute((lane ^ 32) << 2,
                                                     __float_as_int(p)));        // ^32
    if (g4 == 0) out[b] = p + fc_b[0];
}

extern "C" void kernel_launch(void* const* d_in, const int* in_sizes, int n_in,
                              void* d_out, int out_size, void* d_ws, size_t ws_size,
                              hipStream_t stream) {
    const float* x    = (const float*)d_in[0];
    const float* wih  = (const float*)d_in[1];
    const float* whh  = (const float*)d_in[2];
    const float* bias = (const float*)d_in[3];
    const float* fcw  = (const float*)d_in[4];
    const float* fcb  = (const float*)d_in[5];
    float* out = (float*)d_out;

    lstm_bmfma2<<<NB / 16, 64, 0, stream>>>(x, wih, whh, bias, fcw, fcb, out);
}

// Round 25
// 168.834 us; speedup vs baseline: 1.6968x; 1.3124x over previous
//
#include <hip/hip_runtime.h>

#define NB 8192
#define NT 365
#define NF 5
#define NH 10
#define NG 40   // 4*NH
#define GPW 6   // 10-lane groups per wave (lanes 60..63 dead for compute)

// r13 base (best, 171us): one lane owns one hidden unit u (4 gate cols
// f,i,o,g; c[u]; h[u]); 10 ds_bpermute/step broadcast h; g-gate weights
// pre-scaled x2; x prefetched in 8-step register chunks (A/B ping-pong).
//
// NEW vs r13: per-step h/c stores go to a per-wave LDS buffer (2x
// ds_write_b32, cheap); every 32 steps a BURST drains it with fully
// CONTIGUOUS wave64 stores (30x ds_read_b64 + 30x global_store_dwordx2,
// each instr = 512B of one [b][t][u] run). Theory: the per-step scattered
// 40B-run stores (2-3 instrs x ~6-12 transactions, every step, in EVERY
// kernel r3-r24) occupy the memory port and sit in the in-order vmcnt
// queue ahead of the x prefetch loads -- the invariant ~1100cyc/step
// stall. Tail 13 steps store directly.
__global__ __launch_bounds__(256, 1)
void lstm_burst(const float* __restrict__ x,
                const float* __restrict__ w_ih,
                const float* __restrict__ w_hh,
                const float* __restrict__ bias,
                const float* __restrict__ fc_w,
                const float* __restrict__ fc_b,
                float* __restrict__ out)
{
    // per wave: [arr(h/c)][6 groups][32 steps][10 units], g-stride 328 (pad)
    __shared__ float lds[4 * 3936];

    const int tid  = threadIdx.x;
    const int lane = tid & 63;
    const int wv   = tid >> 6;
    const int wid  = (blockIdx.x * 256 + tid) >> 6;  // global wave id
    const int g    = lane / NH;          // group (0..5; 6 => dead)
    const int u    = lane % NH;          // owned hidden unit
    const long b0  = (long)wid * GPW + g;
    const bool alive = (g < GPW) && (b0 < NB);
    const long b   = alive ? b0 : 0;

    float* h_out = out + NB;
    float* c_out = h_out + (size_t)NB * NT * NH;

    // ---- per-lane weights (r13 verbatim) ----
    float wih[NF][4], whh[NH][4], bq[4];
    #pragma unroll
    for (int q = 0; q < 4; ++q) {
        const float gs = (q == 3) ? 2.0f : 1.0f;
        const int col = q * NH + u;
        #pragma unroll
        for (int f = 0; f < NF; ++f) wih[f][q] = w_ih[f * NG + col] * gs;
        #pragma unroll
        for (int j = 0; j < NH; ++j) whh[j][q] = w_hh[j * NG + col] * gs;
        bq[q] = bias[col] * gs;
    }

    int aj[NH];
    #pragma unroll
    for (int j = 0; j < NH; ++j) aj[j] = (g * NH + j) * 4;

    float hAll[NH];
    #pragma unroll
    for (int j = 0; j < NH; ++j) hAll[j] = 0.f;
    float c = 0.f;

    const float* xp = x + (size_t)b * NT * NF;   // 16B-aligned (b*29200)
    float* Lw = &lds[wv * 3936];
    float* wh = Lw + g * 328 + u;          // h slot base (this lane)
    float* wc = wh + 1968;                 // c slot base (arr stride 6*328)

    float A[40], B[40];

#define LD8(dst, t0) { \
    const float4* p4 = reinterpret_cast<const float4*>(xp + (size_t)(t0) * NF); \
    _Pragma("unroll") \
    for (int i = 0; i < 10; ++i) { \
        float4 v = p4[i]; \
        dst[i*4+0] = v.x; dst[i*4+1] = v.y; dst[i*4+2] = v.z; dst[i*4+3] = v.w; } }

#define LDT(dst) { \
    const float4* p4 = reinterpret_cast<const float4*>(xp + (size_t)360 * NF); \
    _Pragma("unroll") \
    for (int i = 0; i < 6; ++i) { \
        float4 v = p4[i]; \
        dst[i*4+0] = v.x; dst[i*4+1] = v.y; dst[i*4+2] = v.z; dst[i*4+3] = v.w; } \
    dst[24] = xp[360 * NF + 24]; }

// shared step math (r13 verbatim); STORE is the only difference
#define STEP_MATH(buf, s) \
    float r0 = bq[0], r1 = bq[1], r2 = bq[2], r3 = bq[3]; \
    _Pragma("unroll") \
    for (int f = 0; f < NF; ++f) { \
        const float xv = buf[(s) * NF + f]; \
        r0 = fmaf(xv, wih[f][0], r0); r1 = fmaf(xv, wih[f][1], r1); \
        r2 = fmaf(xv, wih[f][2], r2); r3 = fmaf(xv, wih[f][3], r3); } \
    _Pragma("unroll") \
    for (int j = 0; j < NH; ++j) { \
        const float hv = hAll[j]; \
        r0 = fmaf(hv, whh[j][0], r0); r1 = fmaf(hv, whh[j][1], r1); \
        r2 = fmaf(hv, whh[j][2], r2); r3 = fmaf(hv, whh[j][3], r3); } \
    const float sf = __builtin_amdgcn_rcpf(1.0f + __expf(-r0)); \
    const float si = __builtin_amdgcn_rcpf(1.0f + __expf(-r1)); \
    const float so = __builtin_amdgcn_rcpf(1.0f + __expf(-r2)); \
    const float tg = fmaf(2.0f, __builtin_amdgcn_rcpf(1.0f + __expf(-r3)), -1.0f); \
    c = fmaf(sf, c, si * tg); \
    const float th = fmaf(2.0f, __builtin_amdgcn_rcpf(1.0f + __expf(-2.0f * c)), -1.0f); \
    const float h = so * th; \
    _Pragma("unroll") \
    for (int j = 0; j < NH; ++j) \
        hAll[j] = __int_as_float(__builtin_amdgcn_ds_bpermute(aj[j], __float_as_int(h)));

// LDS-buffered step: slot is a literal in [0,32)
#define STEPL(buf, s, slot) { \
    STEP_MATH(buf, s) \
    if (alive) { wh[(slot) * 10] = h; wc[(slot) * 10] = c; } }

// direct-store step (tail): hcp/ccp live pointers
#define STEPD(buf, s) { \
    STEP_MATH(buf, s) \
    if (alive) { hcp[(s) * NH] = h; ccp[(s) * NH] = c; } }

#define RUN8L(buf, sl0) { STEPL(buf,0,(sl0)+0) STEPL(buf,1,(sl0)+1) \
    STEPL(buf,2,(sl0)+2) STEPL(buf,3,(sl0)+3) STEPL(buf,4,(sl0)+4) \
    STEPL(buf,5,(sl0)+5) STEPL(buf,6,(sl0)+6) STEPL(buf,7,(sl0)+7) }

// drain 32 steps: 1920 8B-chunks over 12 runs (6 batch x {h,c}) x 160;
// iter i: chunk = i*64 + lane -> run boundary is compile-time
#define BURST(t0) { \
    _Pragma("unroll") \
    for (int i = 0; i < 30; ++i) { \
        const int run0 = (i * 64) / 160; \
        const int lb   = (run0 + 1) * 160 - i * 64;     /* lanes < lb in run0 */ \
        const int run  = (lane < lb) ? run0 : run0 + 1; \
        const int g_   = (lane < lb) ? (run0 % 6) : ((run0 + 1) % 6); \
        const int ar_  = (lane < lb) ? (run0 / 6) : ((run0 + 1) / 6); \
        const int off  = i * 64 + lane - run * 160;     /* [0,160) 8B units */ \
        const long bg  = (long)wid * GPW + g_; \
        if (bg < NB) { \
            const float* ls = Lw + ar_ * 1968 + g_ * 328 + off * 2; \
            float2 v; v.x = ls[0]; v.y = ls[1]; \
            float* gp = (ar_ ? c_out : h_out) + (size_t)bg * NT * NH \
                        + (size_t)(t0) * NH + off * 2; \
            *reinterpret_cast<float2*>(gp) = v; \
        } } }

    LD8(A, 0)
    for (int cc = 0; cc < 22; ++cc) {
        const int t0 = cc * 16;
        LD8(B, t0 + 8)
        if (cc & 1) { RUN8L(A, 16) } else { RUN8L(A, 0) }
        LD8(A, t0 + 16)                  // cc=21 -> t=352..359, in-bounds
        if (cc & 1) { RUN8L(B, 24) } else { RUN8L(B, 8) }
        if (cc & 1) BURST(16 * (cc - 1)) // 32-step window complete
    }
    // t=352..359 in A; tail x (t=360..364) into B; direct stores from here
    float* hcp = h_out + (size_t)b * NT * NH + 352 * NH + u;
    float* ccp = c_out + (size_t)b * NT * NH + 352 * NH + u;
    LDT(B)
    { STEPD(A,0) STEPD(A,1) STEPD(A,2) STEPD(A,3)
      STEPD(A,4) STEPD(A,5) STEPD(A,6) STEPD(A,7) }
    hcp += 8 * NH; ccp += 8 * NH;
    { STEPD(B,0) STEPD(B,1) STEPD(B,2) STEPD(B,3) STEPD(B,4) }  // t=360..364

    // ---- fc head (r13 verbatim) ----
    if (alive && u == 0) {
        float acc = fc_b[0];
        #pragma unroll
        for (int j = 0; j < NH; ++j) acc = fmaf(hAll[j], fc_w[j], acc);
        out[b] = acc;
    }
}

extern "C" void kernel_launch(void* const* d_in, const int* in_sizes, int n_in,
                              void* d_out, int out_size, void* d_ws, size_t ws_size,
                              hipStream_t stream) {
    const float* x    = (const float*)d_in[0];
    const float* wih  = (const float*)d_in[1];
    const float* whh  = (const float*)d_in[2];
    const float* bias = (const float*)d_in[3];
    const float* fcw  = (const float*)d_in[4];
    const float* fcb  = (const float*)d_in[5];
    float* out = (float*)d_out;

    const int nwave  = (NB + GPW - 1) / GPW;          // 1366 waves of work
    const int blocks = (nwave * 64 + 255) / 256;      // 342 blocks
    lstm_burst<<<blocks, 256, 0, stream>>>(x, wih, whh, bias, fcw, fcb, out);
}